// Round 1
// baseline (129.773 us; speedup 1.0000x reference)
//
#include <hip/hip_runtime.h>

// Modulated deformable depthwise conv, B=8 C=128 H=W=64 K=3 PAD=1 STRIDE=1.
// Strategy: per-(b,h,w) bilinear tap metadata computed once, kept in
// registers, reused across a 16-channel chunk. Wave = one w-row (coalesced
// offset/mask loads + output stores); b/channel-group derived from blockIdx
// so they are wave-uniform (scalar dyn_weight loads, SGPR plane base).

#define BB 8
#define CC 128
#define HH 64
#define WW 64
#define KKT 9          // K*K taps
#define CH_CHUNK 16
#define NCG (CC / CH_CHUNK)

__global__ void mdcn_kernel(const float* __restrict__ x,
                            const float* __restrict__ offset,
                            const float* __restrict__ mask,
                            const float* __restrict__ dynw,
                            float* __restrict__ out)
{
    const int blk = blockIdx.x;
    const int hq = blk & 15;          // h / 4
    const int cg = (blk >> 4) & (NCG - 1);
    const int b  = blk >> 7;          // 0..7  (uniform per block)
    const int w  = threadIdx.x & 63;
    const int h  = hq * 4 + (threadIdx.x >> 6);

    const int HW = HH * WW;

    // ---- per-tap bilinear metadata (registers, static-indexed) ----
    float wgt[KKT][4];
    int   ofs[KKT][4];   // byte offsets into one [H][W] fp32 plane

    const float* offp = offset + (size_t)b * (2 * KKT) * HW + h * WW + w;
    const float* mskp = mask   + (size_t)b * KKT * HW       + h * WW + w;

    #pragma unroll
    for (int t = 0; t < KKT; ++t) {
        const float oy = offp[(2 * t)     * HW];
        const float ox = offp[(2 * t + 1) * HW];
        const float m  = mskp[t * HW];
        const float py = (float)(h - 1 + t / 3) + oy;
        const float px = (float)(w - 1 + t % 3) + ox;
        const float fy = floorf(py), fx = floorf(px);
        const float dy = py - fy,    dx = px - fx;
        const int iy0 = (int)fy, ix0 = (int)fx;
        const int iy1 = iy0 + 1, ix1 = ix0 + 1;
        const bool vy0 = (unsigned)iy0 < (unsigned)HH;
        const bool vy1 = (unsigned)iy1 < (unsigned)HH;
        const bool vx0 = (unsigned)ix0 < (unsigned)WW;
        const bool vx1 = (unsigned)ix1 < (unsigned)WW;
        const float omdy = 1.f - dy, omdx = 1.f - dx;
        wgt[t][0] = (vy0 && vx0) ? omdy * omdx * m : 0.f;
        wgt[t][1] = (vy0 && vx1) ? omdy * dx   * m : 0.f;
        wgt[t][2] = (vy1 && vx0) ? dy   * omdx * m : 0.f;
        wgt[t][3] = (vy1 && vx1) ? dy   * dx   * m : 0.f;
        const int cy0 = min(max(iy0, 0), HH - 1);
        const int cy1 = min(max(iy1, 0), HH - 1);
        const int cx0 = min(max(ix0, 0), WW - 1);
        const int cx1 = min(max(ix1, 0), WW - 1);
        ofs[t][0] = (cy0 * WW + cx0) * 4;
        ofs[t][1] = (cy0 * WW + cx1) * 4;
        ofs[t][2] = (cy1 * WW + cx0) * 4;
        ofs[t][3] = (cy1 * WW + cx1) * 4;
    }

    // ---- channel-chunk loop, metadata reused ----
    const int c0 = cg * CH_CHUNK;
    const float* planep = x    + (size_t)(b * CC + c0) * HW;
    const float* wtp    = dynw + (size_t)(b * CC + c0) * KKT;
    float*       outp   = out  + (size_t)(b * CC + c0) * HW + h * WW + w;

    for (int ci = 0; ci < CH_CHUNK; ++ci) {
        const char* pb = (const char*)planep;
        float s = 0.f;
        #pragma unroll
        for (int t = 0; t < KKT; ++t) {
            float v;
            v  = *(const float*)(pb + ofs[t][0]) * wgt[t][0];
            v += *(const float*)(pb + ofs[t][1]) * wgt[t][1];
            v += *(const float*)(pb + ofs[t][2]) * wgt[t][2];
            v += *(const float*)(pb + ofs[t][3]) * wgt[t][3];
            s += v * wtp[ci * KKT + t];
        }
        outp[(size_t)ci * HW] = s;
        planep += HW;
    }
}

extern "C" void kernel_launch(void* const* d_in, const int* in_sizes, int n_in,
                              void* d_out, int out_size, void* d_ws, size_t ws_size,
                              hipStream_t stream) {
    const float* x      = (const float*)d_in[0];
    const float* offset = (const float*)d_in[1];
    const float* mask   = (const float*)d_in[2];
    const float* dynw   = (const float*)d_in[3];
    float* out = (float*)d_out;

    dim3 grid(BB * NCG * (HH / 4));   // 8 * 8 * 16 = 1024 blocks
    dim3 block(256);
    mdcn_kernel<<<grid, block, 0, stream>>>(x, offset, mask, dynw, out);
}

// Round 2
// 43.947 us; speedup vs baseline: 2.9530x; 2.9530x over previous
//
#include <hip/hip_runtime.h>

// Modulated deformable depthwise conv, B=8 C=128 H=W=64 K=3 PAD=1 STRIDE=1.
// Round 1: LDS-staged sampling window. Per block: one (b, channel-group,
// 8-row h-slab). The zero-padded 22x76 sampling window for a channel is
// staged into LDS (double-buffered, next channel's loads issued before
// current channel's compute), and all 36 bilinear-corner gathers become
// LDS reads with no validity masking (pads hold zeros). Out-of-window
// taps (|offset|>=5, P~1e-4) take a wave-uniform-guarded corrective path
// that replays the reference math from global memory.

#define BB 8
#define CC 128
#define HH 64
#define WW 64
#define HWs (HH*WW)
#define KKT 9
#define CH 16              // channels per block
#define NCG (CC/CH)        // 8
#define ROWS 8             // output rows per block
#define NHS (HH/ROWS)      // 8
#define WLO 6              // staged rows above h0: h0-6 .. h0+15
#define WR  22
#define CLO 6              // staged cols left: -6 .. 69
#define WC  76
#define CELLS (WR*WC)      // 1672
#define CELLS_PAD 2048
#define NTHR 512
#define STG (CELLS_PAD/NTHR)   // 4

__global__ __launch_bounds__(NTHR, 4)
void mdcn_kernel(const float* __restrict__ x,
                 const float* __restrict__ offset,
                 const float* __restrict__ mask,
                 const float* __restrict__ dynw,
                 float* __restrict__ out)
{
    __shared__ float lds[2][CELLS_PAD];

    const int blk = blockIdx.x;
    const int hs = blk & (NHS - 1);
    const int cg = (blk >> 3) & (NCG - 1);
    const int b  = blk >> 6;
    const int tid = threadIdx.x;
    const int w = tid & 63;
    const int h0 = hs * ROWS;
    const int h = h0 + (tid >> 6);

    // ---- per-tap metadata (channel-invariant, registers) ----
    float fw[KKT][4];
    int   woff[KKT];          // LDS cell index of top-left corner
    int   badmask = 0;

    const float* offp = offset + (size_t)b * (2 * KKT) * HWs + h * WW + w;
    const float* mskp = mask   + (size_t)b * KKT * HWs       + h * WW + w;

    #pragma unroll
    for (int t = 0; t < KKT; ++t) {
        const float oy = offp[(2 * t)     * HWs];
        const float ox = offp[(2 * t + 1) * HWs];
        const float m  = mskp[t * HWs];
        const float py = (float)(h - 1 + t / 3) + oy;
        const float px = (float)(w - 1 + t % 3) + ox;
        const float fy = floorf(py), fx = floorf(px);
        const float dy = py - fy,    dx = px - fx;
        const int y0 = (int)fy, x0 = (int)fx;
        const bool bad = (y0 < h0 - WLO) || (y0 + 1 > h0 - WLO + WR - 1) ||
                         (x0 < -CLO)     || (x0 + 1 > -CLO + WC - 1);
        const float omdy = 1.f - dy, omdx = 1.f - dx;
        if (bad) {
            badmask |= (1 << t);
            woff[t] = 0;
            fw[t][0] = fw[t][1] = fw[t][2] = fw[t][3] = 0.f;
        } else {
            woff[t] = (y0 - (h0 - WLO)) * WC + (x0 + CLO);
            fw[t][0] = omdy * omdx * m;
            fw[t][1] = omdy * dx   * m;
            fw[t][2] = dy   * omdx * m;
            fw[t][3] = dy   * dx   * m;
        }
    }
    const int anybad = __any(badmask != 0);

    // ---- channel-invariant staging metadata ----
    int gofs[STG];            // element offset into a channel plane, -1 = pad
    #pragma unroll
    for (int k = 0; k < STG; ++k) {
        const int idx = tid + k * NTHR;
        const int row = idx / WC;
        const int col = idx % WC - CLO;
        const int ar  = h0 - WLO + row;
        gofs[k] = ((unsigned)ar < (unsigned)HH && (unsigned)col < (unsigned)WW)
                  ? (ar * WW + col) : -1;
    }

    const float* plane = x    + (size_t)(b * CC + cg * CH) * HWs;
    const float* wtp   = dynw + (size_t)(b * CC + cg * CH) * KKT;
    float*       outp  = out  + (size_t)(b * CC + cg * CH) * HWs + h * WW + w;

    // ---- prologue: stage channel 0 into buffer 0 ----
    #pragma unroll
    for (int k = 0; k < STG; ++k) {
        float v = 0.f;
        if (gofs[k] >= 0) v = plane[gofs[k]];
        lds[0][tid + k * NTHR] = v;
    }
    __syncthreads();

    // ---- channel loop, double-buffered ----
    for (int ci = 0; ci < CH; ++ci) {
        const int p = ci & 1;

        // T14 split: issue next channel's global loads now, write to LDS later
        float stg[STG];
        if (ci + 1 < CH) {
            const float* np = plane + (size_t)(ci + 1) * HWs;
            #pragma unroll
            for (int k = 0; k < STG; ++k) {
                stg[k] = (gofs[k] >= 0) ? np[gofs[k]] : 0.f;
            }
        }

        const float* Lp = lds[p];
        float s = 0.f;
        #pragma unroll
        for (int t = 0; t < KKT; ++t) {
            const float v00 = Lp[woff[t]];
            const float v01 = Lp[woff[t] + 1];
            const float v10 = Lp[woff[t] + WC];
            const float v11 = Lp[woff[t] + WC + 1];
            const float v = v00 * fw[t][0] + v01 * fw[t][1]
                          + v10 * fw[t][2] + v11 * fw[t][3];
            s += v * wtp[ci * KKT + t];
        }

        // rare corrective path for out-of-window taps (exact reference math)
        if (anybad) {
            const float* pl = plane + (size_t)ci * HWs;
            #pragma unroll
            for (int t = 0; t < KKT; ++t) {
                if (badmask & (1 << t)) {
                    const float oy = offp[(2 * t)     * HWs];
                    const float ox = offp[(2 * t + 1) * HWs];
                    const float m  = mskp[t * HWs];
                    const float py = (float)(h - 1 + t / 3) + oy;
                    const float px = (float)(w - 1 + t % 3) + ox;
                    const float fy = floorf(py), fx = floorf(px);
                    const float dy = py - fy,    dx = px - fx;
                    const int y0 = (int)fy, x0 = (int)fx;
                    const int y1 = y0 + 1,  x1 = x0 + 1;
                    const int cy0 = min(max(y0, 0), HH - 1);
                    const int cy1 = min(max(y1, 0), HH - 1);
                    const int cx0 = min(max(x0, 0), WW - 1);
                    const int cx1 = min(max(x1, 0), WW - 1);
                    const float m00 = ((unsigned)y0 < HH && (unsigned)x0 < WW) ? 1.f : 0.f;
                    const float m01 = ((unsigned)y0 < HH && (unsigned)x1 < WW) ? 1.f : 0.f;
                    const float m10 = ((unsigned)y1 < HH && (unsigned)x0 < WW) ? 1.f : 0.f;
                    const float m11 = ((unsigned)y1 < HH && (unsigned)x1 < WW) ? 1.f : 0.f;
                    const float v00 = pl[cy0 * WW + cx0] * m00;
                    const float v01 = pl[cy0 * WW + cx1] * m01;
                    const float v10 = pl[cy1 * WW + cx0] * m10;
                    const float v11 = pl[cy1 * WW + cx1] * m11;
                    const float omdy = 1.f - dy, omdx = 1.f - dx;
                    const float v = v00 * (omdy * omdx) + v01 * (omdy * dx)
                                  + v10 * (dy * omdx)   + v11 * (dy * dx);
                    s += v * m * wtp[ci * KKT + t];
                }
            }
        }

        outp[(size_t)ci * HWs] = s;

        if (ci + 1 < CH) {
            float* Ln = lds[p ^ 1];
            #pragma unroll
            for (int k = 0; k < STG; ++k) {
                Ln[tid + k * NTHR] = stg[k];
            }
        }
        __syncthreads();
    }
}

extern "C" void kernel_launch(void* const* d_in, const int* in_sizes, int n_in,
                              void* d_out, int out_size, void* d_ws, size_t ws_size,
                              hipStream_t stream) {
    const float* x      = (const float*)d_in[0];
    const float* offset = (const float*)d_in[1];
    const float* mask   = (const float*)d_in[2];
    const float* dynw   = (const float*)d_in[3];
    float* out = (float*)d_out;

    dim3 grid(BB * NCG * NHS);   // 8 * 8 * 8 = 512 blocks
    dim3 block(NTHR);
    mdcn_kernel<<<grid, block, 0, stream>>>(x, offset, mask, dynw, out);
}